// Round 1
// baseline (71.757 us; speedup 1.0000x reference)
//
#include <hip/hip_runtime.h>

// Geometry (fixed by the reference)
#define FDIM 16
#define SDIM 512
#define ODIM 32
#define SF   (SDIM * FDIM)    // 8192 per batch row
#define PAIRS (FDIM * ODIM)   // 512 (f,o) pairs
#define NCHUNK 4
#define CH   (SDIM / NCHUNK)  // 128 s-values per chunk

// out[b,o] = relu( bias[o] + sum_f max_s x[b,s,f] * W[s*F+f, o] )
// Key identity: W[(s*FDIM+f)*ODIM + o] = W[s*512 + p], p = f*32+o.
// Thread tq owns pairs p = 4*tq .. 4*tq+3 -> contiguous float4 W loads,
// whole block reads one contiguous 2KB W row per s. x comes from LDS
// (broadcast across the 32 o-lanes sharing an f).
__global__ __launch_bounds__(512) void max_layer_kernel(
    const float* __restrict__ x, const float* __restrict__ W,
    const float* __restrict__ bias, float* __restrict__ out) {
  __shared__ float xs[SF];               // 32 KB: one x row
  __shared__ float red[NCHUNK * PAIRS];  // 8 KB: chunk partial maxes

  const int t = threadIdx.x;
  const int b = blockIdx.x;

  // Stage x row: 2048 float4 loads, coalesced.
  const float4* xin = (const float4*)(x + b * SF);
  float4* xsv = (float4*)xs;
  for (int i = t; i < SF / 4; i += 512) xsv[i] = xin[i];
  __syncthreads();

  const int tq = t & 127;   // pair-group: owns pairs 4*tq..4*tq+3 (same f)
  const int sc = t >> 7;    // s-chunk 0..3
  const int f  = tq >> 3;   // f of the 4 owned pairs (4*tq)>>5 == tq>>3

  const float NEG = -3.402823466e+38f;
  float4 m = make_float4(NEG, NEG, NEG, NEG);

  const float4* wp = (const float4*)W + (size_t)sc * CH * (PAIRS / 4) + tq;
  const float*  xp = xs + sc * CH * FDIM + f;

#pragma unroll 4
  for (int i = 0; i < CH; ++i) {
    float4 w = wp[i * (PAIRS / 4)];   // contiguous 2KB row across block
    float xv = xp[i * FDIM];          // LDS broadcast (8 addrs / wave)
    m.x = fmaxf(m.x, xv * w.x);
    m.y = fmaxf(m.y, xv * w.y);
    m.z = fmaxf(m.z, xv * w.z);
    m.w = fmaxf(m.w, xv * w.w);
  }

  // red[sc*512 + 4*tq + k] = m[k]
  ((float4*)red)[sc * (PAIRS / 4) + tq] = m;
  __syncthreads();

  // Combine the 4 s-chunks per pair.
  float mm = 0.0f;
  if (t < PAIRS) {
    mm = fmaxf(fmaxf(red[t], red[PAIRS + t]),
               fmaxf(red[2 * PAIRS + t], red[3 * PAIRS + t]));
  }
  __syncthreads();
  if (t < PAIRS) red[t] = mm;   // red[p] = max_s x*W for pair p
  __syncthreads();

  // Sum over f per o, add bias, relu, store.
  if (t < ODIM) {
    float s = bias[t];
#pragma unroll
    for (int ff = 0; ff < FDIM; ++ff) s += red[ff * ODIM + t];
    out[b * ODIM + t] = fmaxf(s, 0.0f);
  }
}

extern "C" void kernel_launch(void* const* d_in, const int* in_sizes, int n_in,
                              void* d_out, int out_size, void* d_ws, size_t ws_size,
                              hipStream_t stream) {
  const float* x    = (const float*)d_in[0];
  const float* W    = (const float*)d_in[1];
  const float* bias = (const float*)d_in[2];
  float* out        = (float*)d_out;
  max_layer_kernel<<<dim3(256), dim3(512), 0, stream>>>(x, W, bias, out);
}

// Round 2
// 69.442 us; speedup vs baseline: 1.0333x; 1.0333x over previous
//
#include <hip/hip_runtime.h>

// Geometry (fixed by the reference)
#define FDIM 16
#define SDIM 512
#define ODIM 32
#define SF   (SDIM * FDIM)   // 8192 floats per batch row
#define PAIRS 512            // (f,o) pairs; W[s*512 + p], p = f*32+o
#define NB   8               // batches per block (W reuse factor)
#define SC   32              // shifts per block
#define NSC  (SDIM / SC)     // 16 s-chunks
#define NBG  (256 / NB)      // 32 batch groups

// Phase 1: partial max over an s-chunk, for NB batches x all 512 pairs.
// Thread tq (=t&127) owns pairs 4tq..4tq+3 (one f); th (=t>>7) splits the
// 32-s chunk in half. Each W float4 is loaded ONCE and reused across the
// NB=8 batch accumulators -> W L2 traffic = (256/NB) MB = 32 MB total.
__global__ __launch_bounds__(256) void max_layer_phase1(
    const float* __restrict__ x, const float* __restrict__ W,
    float* __restrict__ part) {
  __shared__ float xs[NB * SC * FDIM];  // 16 KB, [b][s][f]
  __shared__ float red[NB * PAIRS];     // 16 KB, th=1 partials

  const int t  = threadIdx.x;
  const int bg = blockIdx.x / NSC;
  const int sc = blockIdx.x % NSC;

  // Stage x chunk: per b, 2 KB contiguous; fully coalesced float4.
  const float4* xin = (const float4*)x;
  float4* xs4 = (float4*)xs;
  for (int i = t; i < NB * SC * FDIM / 4; i += 256) {
    int b   = i / (SC * FDIM / 4);   // /128
    int off = i % (SC * FDIM / 4);
    xs4[i] = xin[(size_t)(bg * NB + b) * (SF / 4) + sc * (SC * FDIM / 4) + off];
  }
  __syncthreads();

  const int tq = t & 127;
  const int th = t >> 7;          // s-half 0/1
  const int f  = tq >> 3;         // f of owned pairs

  const float NEG = -3.402823466e+38f;
  float4 macc[NB];
#pragma unroll
  for (int b = 0; b < NB; ++b) macc[b] = make_float4(NEG, NEG, NEG, NEG);

  const float4* wp = (const float4*)W + (size_t)(sc * SC) * (PAIRS / 4) + tq;

#pragma unroll 4
  for (int j = 0; j < SC / 2; ++j) {
    const int s = th * (SC / 2) + j;
    float4 w = wp[s * (PAIRS / 4)];      // one 2KB W row / s, shared by 2 waves
    const float* xp = xs + s * FDIM + f;
#pragma unroll
    for (int b = 0; b < NB; ++b) {
      float xv = xp[b * SC * FDIM];      // LDS broadcast (8 lanes/addr)
      macc[b].x = fmaxf(macc[b].x, xv * w.x);
      macc[b].y = fmaxf(macc[b].y, xv * w.y);
      macc[b].z = fmaxf(macc[b].z, xv * w.z);
      macc[b].w = fmaxf(macc[b].w, xv * w.w);
    }
  }

  // Combine the two s-halves, write partials: part[(b)*NSC + sc][p]
  if (th == 1) {
#pragma unroll
    for (int b = 0; b < NB; ++b) ((float4*)red)[b * 128 + tq] = macc[b];
  }
  __syncthreads();
  if (th == 0) {
#pragma unroll
    for (int b = 0; b < NB; ++b) {
      float4 o = ((float4*)red)[b * 128 + tq];
      o.x = fmaxf(o.x, macc[b].x);
      o.y = fmaxf(o.y, macc[b].y);
      o.z = fmaxf(o.z, macc[b].z);
      o.w = fmaxf(o.w, macc[b].w);
      ((float4*)part)[((size_t)(bg * NB + b) * NSC + sc) * (PAIRS / 4) + tq] = o;
    }
  }
}

// Phase 2: max over the 16 chunk-partials per (b,p), then f-sum + bias + relu.
__global__ __launch_bounds__(256) void max_layer_phase2(
    const float* __restrict__ part, const float* __restrict__ bias,
    float* __restrict__ out) {
  __shared__ float red[PAIRS];
  const int t = threadIdx.x;
  const int b = blockIdx.x;
  const float* pb = part + (size_t)b * NSC * PAIRS;
  for (int p = t; p < PAIRS; p += 256) {
    float m = pb[p];
#pragma unroll
    for (int c = 1; c < NSC; ++c) m = fmaxf(m, pb[c * PAIRS + p]);
    red[p] = m;
  }
  __syncthreads();
  if (t < ODIM) {
    float s = bias[t];
#pragma unroll
    for (int ff = 0; ff < FDIM; ++ff) s += red[ff * ODIM + t];
    out[b * ODIM + t] = fmaxf(s, 0.0f);
  }
}

extern "C" void kernel_launch(void* const* d_in, const int* in_sizes, int n_in,
                              void* d_out, int out_size, void* d_ws, size_t ws_size,
                              hipStream_t stream) {
  const float* x    = (const float*)d_in[0];
  const float* W    = (const float*)d_in[1];
  const float* bias = (const float*)d_in[2];
  float* out        = (float*)d_out;
  float* part       = (float*)d_ws;   // 256*16*512*4 = 8 MB of scratch

  max_layer_phase1<<<dim3(NBG * NSC), dim3(256), 0, stream>>>(x, W, part);
  max_layer_phase2<<<dim3(256), dim3(256), 0, stream>>>(part, bias, out);
}